// Round 7
// baseline (364.800 us; speedup 1.0000x reference)
//
#include <hip/hip_runtime.h>
#include <hip/hip_bf16.h>

// Bahdanau attention (R7):
//   q = dh @ Wq^T                                  (f32, tiny)
//   Wk -> bf16 (2 MB)
//   scores[b,s] = v . tanh(q[b] + Wk @ enc[b,s])   fused GEMM: BM=256 x BN=256 x BK=32,
//       512 thr / 8 waves (2Mx4N, wave tile 128x64, acc[8][4]=128 VGPR, 2 waves/SIMD),
//       enc read once as f32 (in-reg cvt), B via global_load_lds (swizzle folded into
//       per-lane GLOBAL address, LDS dest linear - m173 pattern), A reg-staged with
//       swizzled ds_write. XOR swizzle: 16B-slot q ^= (row>>1)&3 -> 2-way banks.
//       2-phase pipeline, 64 KB LDS dbuf, XCD swizzle: strip's 4 N-tiles share an XCD.
//   attn = softmax(mask ? scores : -1e9)
//   ctx[b,e] = sum_s attn[b,s]*enc[b,s,e]          (memory-bound, f32, L3-warm)

#define NB 32
#define SS 2048
#define HD 1024
#define HE 1024
#define MM (NB * SS)   // 65536 rows
#define NT 32          // K-tiles = HE/32

typedef float f32x4 __attribute__((ext_vector_type(4)));
typedef short bf16x8 __attribute__((ext_vector_type(8)));
typedef short short4v __attribute__((ext_vector_type(4)));

static __device__ __forceinline__ short f2bf(float f) {
    union { __hip_bfloat16 h; short s; } u;
    u.h = __float2bfloat16(f);
    return u.s;
}

// async global->LDS, 16B per lane; LDS dest = wave-uniform base + lane*16.
static __device__ __forceinline__ void gload16(const void* g, const void* l) {
    __builtin_amdgcn_global_load_lds(
        (const __attribute__((address_space(1))) void*)(uintptr_t)(g),
        (__attribute__((address_space(3))) void*)(unsigned)(uintptr_t)(l),
        16, 0, 0);
}

// ---------------- f32 -> bf16 conversion (Wk only, 1M elems) ----------------
__global__ __launch_bounds__(256) void cvt_bf16_kernel(const float* __restrict__ in,
                                                       short* __restrict__ out, int n8) {
    int i = blockIdx.x * 256 + threadIdx.x;
    const int stride = gridDim.x * 256;
    for (; i < n8; i += stride) {
        const f32x4 a = *(const f32x4*)(in + (long)i * 8);
        const f32x4 b = *(const f32x4*)(in + (long)i * 8 + 4);
        bf16x8 o;
        o[0] = f2bf(a[0]); o[1] = f2bf(a[1]); o[2] = f2bf(a[2]); o[3] = f2bf(a[3]);
        o[4] = f2bf(b[0]); o[5] = f2bf(b[1]); o[6] = f2bf(b[2]); o[7] = f2bf(b[3]);
        *(bf16x8*)(out + (long)i * 8) = o;
    }
}

// ---------------- q = dh @ Wq^T : one wave per output column d ----------------
__global__ __launch_bounds__(256) void qproj_kernel(const float* __restrict__ dh,
                                                    const float* __restrict__ Wq,
                                                    float* __restrict__ q) {
    const int wid  = threadIdx.x >> 6;
    const int lane = threadIdx.x & 63;
    const int d    = blockIdx.x * 4 + wid;
    const float* wrow = Wq + (long)d * HD + lane * 16;
    f32x4 w0 = *(const f32x4*)(wrow + 0);
    f32x4 w1 = *(const f32x4*)(wrow + 4);
    f32x4 w2 = *(const f32x4*)(wrow + 8);
    f32x4 w3 = *(const f32x4*)(wrow + 12);
    for (int b = 0; b < NB; ++b) {
        const float* drow = dh + b * HD + lane * 16;
        f32x4 d0 = *(const f32x4*)(drow + 0);
        f32x4 d1 = *(const f32x4*)(drow + 4);
        f32x4 d2 = *(const f32x4*)(drow + 8);
        f32x4 d3 = *(const f32x4*)(drow + 12);
        f32x4 s4 = w0 * d0 + w1 * d1 + w2 * d2 + w3 * d3;
        float dot = s4[0] + s4[1] + s4[2] + s4[3];
        #pragma unroll
        for (int off = 32; off > 0; off >>= 1)
            dot += __shfl_xor(dot, off, 64);
        if (lane == 0) q[b * HD + d] = dot;
    }
}

// ---------------- fused score GEMM: 256 rows x 256 cols per block ----------------
// LDS layout [256 rows][32 shorts] with XOR swizzle: byte-in-row ^= ((row>>1)&3)<<4.
// Read-side XOR is the per-thread constant kread (rows are multiples of 16 + frow).
__global__ __launch_bounds__(512, 2) void score_fused_kernel(const float* __restrict__ enc,
                                                             const short* __restrict__ wkb,
                                                             const float* __restrict__ qv,
                                                             const float* __restrict__ ven,
                                                             float* __restrict__ sp) {
    __shared__ __align__(16) short As[2][256 * 32];   // 2 x 16 KB
    __shared__ __align__(16) short Bs[2][256 * 32];   // 2 x 16 KB

    // XCD swizzle: strip's 4 N-tiles co-resident on one XCD (A + B L2 reuse)
    const int bid    = blockIdx.x;
    const int xcd    = bid & 7;
    const int slot   = bid >> 3;                // 0..127
    const int mstrip = xcd * 32 + (slot >> 2);  // 0..255
    const int nt     = slot & 3;                // N quarter of 1024

    const int tid  = threadIdx.x;
    const int lane = tid & 63;
    const int wid  = tid >> 6;            // 0..7
    const int wr   = wid >> 2;            // 0..1  (M half: 128 rows)
    const int wc   = wid & 3;             // 0..3  (N quarter: 64 cols)
    const long mbase = (long)mstrip * 256;
    const int  nbase = nt * 256;

    f32x4 acc[8][4];
    #pragma unroll
    for (int m = 0; m < 8; ++m)
        #pragma unroll
        for (int n = 0; n < 4; ++n)
            acc[m][n] = (f32x4){0.f, 0.f, 0.f, 0.f};

    // ---- A staging map: 2048 f32x4 chunks/K-step; thread covers c = j*512+tid, j=0..3
    // chunk c -> row j*64 + (tid>>3), f32-col (tid&7)*4
    const int ar = tid >> 3;                      // row within 64-row group
    const float* ap0 = enc + (mbase + ar) * (long)HE + (tid & 7) * 4;
    const float* ap1 = ap0 + 64 * (long)HE;
    const float* ap2 = ap1 + 64 * (long)HE;
    const float* ap3 = ap2 + 64 * (long)HE;
    // swizzled ds_write byte offsets (constant per thread, s_w = (tid>>4)&3)
    const int awb = (((tid & 7) * 8) ^ (((tid >> 4) & 3) << 4));
    const int aw0 = (ar)       * 64 + awb;
    const int aw1 = (ar + 64)  * 64 + awb;
    const int aw2 = (ar + 128) * 64 + awb;
    const int aw3 = (ar + 192) * 64 + awb;

    // ---- B staging: 1024 16B chunks/K-step; thread covers c = j*512+tid, j=0..1
    // chunk c -> B-row j*128 + (tid>>2); global k pre-swizzled: q' = (tid&3) ^ ((tid>>3)&3)
    const short* bp0 = wkb + (long)(nbase + (tid >> 2)) * HE
                           + (((tid & 3) ^ ((tid >> 3) & 3)) * 8);
    const short* bp1 = bp0 + 128 * (long)HE;
    const int bd0 = (wid * 64) * 16;          // LDS byte dest base (linear), j=0
    const int bd1 = (512 + wid * 64) * 16;    // j=1

    // ---- frag read constants: kread = swizzled 16B slot, same for A and B, all frags
    const int frow  = lane & 15;
    const int kread = (((lane >> 4) ^ ((lane >> 1) & 3)) << 4);

    // ---- prologue: stage tile 0 ----
    {
        f32x4 a0 = *(const f32x4*)(ap0);
        f32x4 a1 = *(const f32x4*)(ap1);
        f32x4 a2 = *(const f32x4*)(ap2);
        f32x4 a3 = *(const f32x4*)(ap3);
        gload16(bp0, (char*)Bs[0] + bd0);
        gload16(bp1, (char*)Bs[0] + bd1);
        short4v v0, v1, v2, v3;
        v0[0]=f2bf(a0[0]); v0[1]=f2bf(a0[1]); v0[2]=f2bf(a0[2]); v0[3]=f2bf(a0[3]);
        v1[0]=f2bf(a1[0]); v1[1]=f2bf(a1[1]); v1[2]=f2bf(a1[2]); v1[3]=f2bf(a1[3]);
        v2[0]=f2bf(a2[0]); v2[1]=f2bf(a2[1]); v2[2]=f2bf(a2[2]); v2[3]=f2bf(a2[3]);
        v3[0]=f2bf(a3[0]); v3[1]=f2bf(a3[1]); v3[2]=f2bf(a3[2]); v3[3]=f2bf(a3[3]);
        *(short4v*)((char*)As[0] + aw0) = v0;
        *(short4v*)((char*)As[0] + aw1) = v1;
        *(short4v*)((char*)As[0] + aw2) = v2;
        *(short4v*)((char*)As[0] + aw3) = v3;
        __syncthreads();
    }

    for (int kt = 0; kt < NT; ++kt) {
        const int cur = kt & 1;

        // stage next tile: A f32 loads first (oldest in vmcnt queue -> cvt's implicit
        // wait leaves the younger B gloads in flight), then B gloads.
        f32x4 a0, a1, a2, a3;
        if (kt + 1 < NT) {
            const int ko = (kt + 1) * 32;
            a0 = *(const f32x4*)(ap0 + ko);
            a1 = *(const f32x4*)(ap1 + ko);
            a2 = *(const f32x4*)(ap2 + ko);
            a3 = *(const f32x4*)(ap3 + ko);
            gload16(bp0 + ko, (char*)Bs[cur ^ 1] + bd0);
            gload16(bp1 + ko, (char*)Bs[cur ^ 1] + bd1);
        }

        // compute on current buffers (swizzled reads: row*64 + kread)
        bf16x8 af[8], bfr[4];
        #pragma unroll
        for (int m = 0; m < 8; ++m)
            af[m] = *(const bf16x8*)((const char*)As[cur] + (wr * 128 + m * 16 + frow) * 64 + kread);
        #pragma unroll
        for (int n = 0; n < 4; ++n)
            bfr[n] = *(const bf16x8*)((const char*)Bs[cur] + (wc * 64 + n * 16 + frow) * 64 + kread);
        #pragma unroll
        for (int m = 0; m < 8; ++m)
            #pragma unroll
            for (int n = 0; n < 4; ++n)
                acc[m][n] = __builtin_amdgcn_mfma_f32_16x16x32_bf16(af[m], bfr[n], acc[m][n], 0, 0, 0);

        if (kt + 1 < NT) {
            short4v v0, v1, v2, v3;
            v0[0]=f2bf(a0[0]); v0[1]=f2bf(a0[1]); v0[2]=f2bf(a0[2]); v0[3]=f2bf(a0[3]);
            v1[0]=f2bf(a1[0]); v1[1]=f2bf(a1[1]); v1[2]=f2bf(a1[2]); v1[3]=f2bf(a1[3]);
            v2[0]=f2bf(a2[0]); v2[1]=f2bf(a2[1]); v2[2]=f2bf(a2[2]); v2[3]=f2bf(a2[3]);
            v3[0]=f2bf(a3[0]); v3[1]=f2bf(a3[1]); v3[2]=f2bf(a3[2]); v3[3]=f2bf(a3[3]);
            *(short4v*)((char*)As[cur ^ 1] + aw0) = v0;
            *(short4v*)((char*)As[cur ^ 1] + aw1) = v1;
            *(short4v*)((char*)As[cur ^ 1] + aw2) = v2;
            *(short4v*)((char*)As[cur ^ 1] + aw3) = v3;
            // drain B gloads (issued ~2500 cyc ago -> near-zero stall) + LDS ops, sync
            asm volatile("s_waitcnt vmcnt(0) lgkmcnt(0)\n\ts_barrier" ::: "memory");
        }
    }

    // ---- epilogue: partial score = sum over this wave's 64 cols of v[c]*tanh(q[b,c]+k)
    // C/D layout: col = lane&15 (N), row = (lane>>4)*4 + reg (M)
    const int bb = (int)(mbase >> 11);
    float qq[4], vv[4];
    #pragma unroll
    for (int n = 0; n < 4; ++n) {
        const int c = nbase + wc * 64 + n * 16 + frow;
        qq[n] = qv[bb * HD + c];
        vv[n] = ven[c];
    }
    float p[8][4];
    #pragma unroll
    for (int m = 0; m < 8; ++m) {
        #pragma unroll
        for (int rg = 0; rg < 4; ++rg) {
            float s = 0.f;
            #pragma unroll
            for (int n = 0; n < 4; ++n) {
                const float x = acc[m][n][rg] + qq[n];
                const float e = __expf(2.f * x);
                const float t = 1.f - 2.f * __builtin_amdgcn_rcpf(e + 1.f);
                s += vv[n] * t;
            }
            #pragma unroll
            for (int msk = 1; msk <= 8; msk <<= 1)
                s += __shfl_xor(s, msk, 64);   // reduce over 16-lane col group
            p[m][rg] = s;
        }
    }
    if ((lane & 15) == 0) {
        const int g = lane >> 4;
        float* dst = sp + (long)(nt * 4 + wc) * MM;   // 16 deterministic partial slots
        #pragma unroll
        for (int m = 0; m < 8; ++m)
            #pragma unroll
            for (int rg = 0; rg < 4; ++rg)
                dst[mbase + wr * 128 + m * 16 + g * 4 + rg] = p[m][rg];
    }
}

// ---------------- mask + softmax over S per batch ----------------
__global__ __launch_bounds__(256) void softmax_kernel(const float* __restrict__ sp,
                                                      const int* __restrict__ mask,
                                                      float* __restrict__ attn) {
    const int b = blockIdx.x;
    const int tid = threadIdx.x;
    const int lane = tid & 63;
    const int wid = tid >> 6;
    __shared__ float red[4];
    float sc[8];
    float mx = -3.0e38f;
    #pragma unroll
    for (int i = 0; i < 8; ++i) {
        const int s = tid + i * 256;
        float v = 0.f;
        #pragma unroll
        for (int k = 0; k < 16; ++k)
            v += sp[(long)k * MM + b * SS + s];
        if (mask[b * SS + s] == 0) v = -1e9f;
        sc[i] = v;
        mx = fmaxf(mx, v);
    }
    #pragma unroll
    for (int off = 32; off > 0; off >>= 1)
        mx = fmaxf(mx, __shfl_xor(mx, off, 64));
    if (lane == 0) red[wid] = mx;
    __syncthreads();
    mx = fmaxf(fmaxf(red[0], red[1]), fmaxf(red[2], red[3]));
    __syncthreads();
    float sum = 0.f;
    #pragma unroll
    for (int i = 0; i < 8; ++i) {
        const float e = __expf(sc[i] - mx);
        sc[i] = e;
        sum += e;
    }
    #pragma unroll
    for (int off = 32; off > 0; off >>= 1)
        sum += __shfl_xor(sum, off, 64);
    if (lane == 0) red[wid] = sum;
    __syncthreads();
    sum = red[0] + red[1] + red[2] + red[3];
    const float inv = 1.f / sum;
    #pragma unroll
    for (int i = 0; i < 8; ++i)
        attn[b * SS + tid + i * 256] = sc[i] * inv;
}

// ---------------- context: partial weighted sums over s-chunks (f32 enc) ----------------
__global__ __launch_bounds__(256) void ctx_partial_kernel(const float* __restrict__ enc,
                                                          const float* __restrict__ attn,
                                                          float* __restrict__ cp) {
    const int b = blockIdx.x >> 5;
    const int chunk = blockIdx.x & 31;
    const int tid = threadIdx.x;
    const float* ep = enc + ((long)b * SS + chunk * 64) * HE + tid * 4;
    const float* ap = attn + b * SS + chunk * 64;
    f32x4 acc = (f32x4){0.f, 0.f, 0.f, 0.f};
    #pragma unroll 4
    for (int s = 0; s < 64; ++s) {
        const float w = ap[s];
        const f32x4 v = *(const f32x4*)(ep + (long)s * HE);
        acc += w * v;
    }
    *(f32x4*)(cp + ((long)(b * 32 + chunk)) * HE + tid * 4) = acc;
}

__global__ __launch_bounds__(256) void ctx_reduce_kernel(const float* __restrict__ cp,
                                                         float* __restrict__ out) {
    const int o = blockIdx.x * 256 + threadIdx.x;
    const int b = o >> 10;
    const int e = o & 1023;
    float s = 0.f;
    #pragma unroll
    for (int c = 0; c < 32; ++c)
        s += cp[((long)(b * 32 + c)) * HE + e];
    out[o] = s;
}

extern "C" void kernel_launch(void* const* d_in, const int* in_sizes, int n_in,
                              void* d_out, int out_size, void* d_ws, size_t ws_size,
                              hipStream_t stream) {
    const float* dh   = (const float*)d_in[0];
    const float* enc  = (const float*)d_in[1];
    const int*   mask = (const int*)d_in[2];
    const float* Wq   = (const float*)d_in[3];
    const float* Wk   = (const float*)d_in[4];
    const float* Ve   = (const float*)d_in[5];

    float* out  = (float*)d_out;
    float* ctx  = out;
    float* attn = out + NB * HD;

    float* ws  = (float*)d_ws;
    float* wq_ = ws;                           // 32768 f
    float* sp  = ws + 32768;                   // 16 * 65536 f (4 MB)
    float* cp  = sp + 16 * (long)MM;           // 32*32*1024 f (4 MB)
    short* wkb = (short*)(cp + 32 * 32 * HE);  // 1M bf16 (2 MB)

    qproj_kernel<<<256, 256, 0, stream>>>(dh, Wq, wq_);
    cvt_bf16_kernel<<<512, 256, 0, stream>>>(Wk, wkb, HD * HE / 8);
    score_fused_kernel<<<1024, 512, 0, stream>>>(enc, wkb, wq_, Ve, sp);
    softmax_kernel<<<32, 256, 0, stream>>>(sp, mask, attn);
    ctx_partial_kernel<<<1024, 256, 0, stream>>>(enc, attn, cp);
    ctx_reduce_kernel<<<128, 256, 0, stream>>>(cp, ctx);
}